// Round 1
// baseline (158.120 us; speedup 1.0000x reference)
//
#include <hip/hip_runtime.h>
#include <hip/hip_bf16.h>

// PCNN recurrence: x[B,T,L], sequential over T, 3-tap spatial coupling per step.
// Halo-redundant tiling: C=512 outputs/block, H=64 halo each side (>= T), so
// blocks are fully independent (errors from unknown tile edges propagate 1
// element/step inward and never reach the central C region).
#define BB 32
#define TT 64
#define LL 8192
#define CC 512
#define HH 64
#define RR (CC + 2 * HH)      // 640 region elems
#define NTHREADS (RR / 2)     // 320 threads, 2 contiguous elems each
#define NCHUNK (LL / CC)      // 16

__device__ __forceinline__ float fsigmoid(float z) {
    float ex = __expf(-z);
    return __fdividef(1.0f, 1.0f + ex);
}

__global__ __launch_bounds__(NTHREADS) void pcnn_kernel(
    const float* __restrict__ x, const float* __restrict__ wptr,
    float* __restrict__ out)
{
    // double-buffered y exchange; only the +/-1 neighbors come from LDS
    __shared__ float ylds[2 * RR];

    const int tid   = threadIdx.x;
    const int blk   = blockIdx.x;
    const int chunk = blk & (NCHUNK - 1);
    const int b     = blk >> 4;

    const float w0 = wptr[0], w1 = wptr[1], w2 = wptr[2];
    const float df = 0.90483741803595957f;  // exp(-0.1)
    const float dl = 0.36787944117144233f;  // exp(-1)
    const float de = 0.36787944117144233f;  // exp(-1)

    const int r0 = 2 * tid;                 // region index of first element
    const int g0 = chunk * CC - HH + r0;    // global column of first element
    // g0 is even and LL is even -> both elements valid or both invalid
    const bool valid = (g0 >= 0) && (g0 < LL);
    const bool store_en = (r0 >= HH) && (r0 < HH + CC);

    // zero-init both buffers (y starts at 0 everywhere)
    ylds[r0] = 0.0f; ylds[r0 + 1] = 0.0f;
    ylds[RR + r0] = 0.0f; ylds[RR + r0 + 1] = 0.0f;
    __syncthreads();

    float f0 = 0.f, f1 = 0.f, l0 = 0.f, l1 = 0.f;
    float e0 = 10.f, e1 = 10.f, y0 = 0.f, y1 = 0.f;

    const float* xrow = x + (size_t)b * TT * LL;
    float*       orow = out + (size_t)b * TT * LL;

    // prefetch step 0
    float2 xc = valid ? *(const float2*)(xrow + g0) : make_float2(0.f, 0.f);

    int cur = 0;
    for (int t = 0; t < TT; ++t) {
        // prefetch next step's x (independent of this step's compute)
        float2 xn = make_float2(0.f, 0.f);
        if ((t + 1 < TT) && valid)
            xn = *(const float2*)(xrow + (size_t)(t + 1) * LL + g0);

        // neighbor y from LDS (previous step's values live in buffer `cur`)
        float yl = (r0 == 0)       ? 0.f : ylds[cur * RR + r0 - 1];
        float yr = (r0 + 2 >= RR)  ? 0.f : ylds[cur * RR + r0 + 2];

        // element 0: neighbors (yl, y1); element 1: neighbors (y0, yr) — all OLD y
        f0 = df * f0 + xc.x + (w0 * yl + w1 * y0 + w2 * y1);
        f1 = df * f1 + xc.y + (w0 * y0 + w1 * y1 + w2 * yr);
        l0 = dl * l0 + yl + y1;
        l1 = dl * l1 + y0 + yr;
        float u0 = f0 * (1.0f + 0.5f * l0);
        float u1 = f1 * (1.0f + 0.5f * l1);
        e0 = de * e0 + 10.0f * y0;
        e1 = de * e1 + 10.0f * y1;

        float ny0 = valid ? fsigmoid(u0 - e0) : 0.f;
        float ny1 = valid ? fsigmoid(u1 - e1) : 0.f;
        y0 = ny0; y1 = ny1;

        const int nxt = cur ^ 1;
        *(float2*)&ylds[nxt * RR + r0] = make_float2(y0, y1);  // 8B-aligned

        if (store_en)
            *(float2*)(orow + (size_t)t * LL + g0) = make_float2(y0, y1);

        __syncthreads();  // old-buf reads done AND new-buf writes visible
        cur = nxt;
        xc = xn;
    }
}

extern "C" void kernel_launch(void* const* d_in, const int* in_sizes, int n_in,
                              void* d_out, int out_size, void* d_ws, size_t ws_size,
                              hipStream_t stream) {
    const float* x = (const float*)d_in[0];
    const float* w = (const float*)d_in[1];
    float* out = (float*)d_out;
    pcnn_kernel<<<dim3(BB * NCHUNK), dim3(NTHREADS), 0, stream>>>(x, w, out);
}